// Round 5
// baseline (126.115 us; speedup 1.0000x reference)
//
#include <hip/hip_runtime.h>

// Hapke BRDF — elementwise, N=1M.
// R5 = R4 math (polynomial acos, half-angle identities, native rcp/exp/log/sin,
// consolidated reciprocals) + vectorized 12-byte record loads/stores.
// R4 evidence: math cuts stopped paying (26.2 -> 25.3 us) — bound moved to
// L1/TA issue: 3x stride-3 dword loads per vec3 array = 36 line-transactions
// per wave per array. One global_load_dwordx3 per record = 12. VMEM instrs
// 24 -> 10 per thread, zero register-pressure change (R3's batching mistake).

#define PIF  3.14159265358979323846f
#define EPSF 1e-5f

struct f3 { float x, y, z; };   // 12 B, align 4 -> global_load_dwordx3

__device__ __forceinline__ float rcp(float x)  { return __builtin_amdgcn_rcpf(x); }
__device__ __forceinline__ float rsq(float x)  { return __builtin_amdgcn_rsqf(x); }
__device__ __forceinline__ float sqf(float x)  { return __builtin_amdgcn_sqrtf(x); }
__device__ __forceinline__ float nz(float y, float r) { return (y != y) ? r : y; }
__device__ __forceinline__ float clamp1(float x) { return fminf(fmaxf(x, -1.0f), 1.0f); }
// Abramowitz-Stegun 4.4.45: |err| <= 6.7e-5 rad; phi only feeds phi/PI * E1
// inside a denominator >= ~0.9 — impact ~2e-5 vs 3.18 threshold.
__device__ __forceinline__ float acos_poly(float x) {
    float a = fabsf(x);
    float r = sqf(1.0f - a) *
              (1.5707288f + a * (-0.2121144f + a * (0.0742610f + a * (-0.0187293f))));
    return (x >= 0.0f) ? r : (PIF - r);
}

__global__ __launch_bounds__(256)
void hapke_kernel(const f3* __restrict__ pts2l, const f3* __restrict__ pts2c,
                  const f3* __restrict__ normal, const f3* __restrict__ w,
                  const f3* __restrict__ b, const f3* __restrict__ c,
                  const float* __restrict__ theta, const float* __restrict__ h,
                  const float* __restrict__ B0, f3* __restrict__ out, int N)
{
    int idx = blockIdx.x * blockDim.x + threadIdx.x;
    if (idx >= N) return;

    f3 L = pts2l[idx];
    f3 V = pts2c[idx];
    f3 Nn = normal[idx];
    f3 wv = w[idx];
    f3 bv = b[idx];
    f3 cc = c[idx];

    // ci, cv in [0,1] (l,v flipped into normal's hemisphere by setup)
    float ci = clamp1(Nn.x*L.x + Nn.y*L.y + Nn.z*L.z);
    float cv = clamp1(Nn.x*V.x + Nn.y*V.y + Nn.z*V.z);
    float cg = clamp1(L.x*V.x + L.y*V.y + L.z*V.z);
    float si = sqf(1.0f - ci*ci);            // sin(acos x) — exact
    float sv = sqf(1.0f - cv*cv);
    float cphi = clamp1((cg - ci*cv) * rcp(si*sv + 1e-8f));
    float phipi = acos_poly(cphi) * (1.0f / PIF);

    // ff = exp(-2 tan((phi+EPS)/2)) via half-angle; cphi==-1 is the ref's tan
    // overflow -> ff=inf -> NaN -> shad=0 path, preserved explicitly.
    float ffu = (1.0f - cphi) * rcp(1.0f + cphi);
    float ff  = (cphi <= -1.0f) ? __builtin_inff() : __expf(-2.0f * sqf(ffu));

    float th = theta[idx];
    float s = __sinf(th + EPSF), cth = __cosf(th + EPSF);
    float tt     = s * rcp(cth);             // tan(th+EPS); reused for tan(th), diff <= 2e-5
    float cot_th = cth * rcp(s);
    float cot_i  = ci * rcp(si);             // si=0 -> inf -> E*=0 (ref limit)
    float cot_e  = cv * rcp(sv);

    float E1i = nz(__expf(-(2.0f/PIF) * cot_th * cot_i), 0.0f);
    float E1e = nz(__expf(-(2.0f/PIF) * cot_th * cot_e), 0.0f);
    float ct2 = cot_th * cot_th;
    float E2i = nz(__expf(-(1.0f/PIF) * ct2 * cot_i*cot_i), 0.0f);
    float E2e = nz(__expf(-(1.0f/PIF) * ct2 * cot_e*cot_e), 0.0f);

    float chit = rsq(1.0f + PIF * tt * tt);
    float etai = nz(chit * (ci + si * tt * (E2i * rcp(2.0f - E1i))), 0.0f);
    float etae = nz(chit * (cv + sv * tt * (E2e * rcp(2.0f - E1e))), 0.0f);

    float sp2 = 0.5f * (1.0f - cphi);        // sin^2(phi/2) — exact half-angle
    bool  ile = (ci >= cv);                  // sza <= vza (branches continuous at tie)
    float Ea  = ile ? E1e : E1i;             // shared denominator: select, then ONE rcp
    float Eb  = ile ? E1i : E1e;
    float rd  = rcp(2.0f - Ea - phipi * Eb);
    float ymu  = (ile ? (E2e - sp2*E2i)       : (cphi*E2i + sp2*E2e)) * rd;
    float ymu0 = (ile ? (cphi*E2e + sp2*E2i)  : (E2i - sp2*E2e)) * rd;
    float cv_e = nz(chit * (cv + sv * tt * ymu ), cv);    // _mu_eff
    float ci_e = nz(chit * (ci + si * tt * ymu0), ci);    // _mu0_eff

    // _S (shadowing)
    float r_etai = rcp(etai), r_etae = rcp(etae);
    float ci_etai = ci * r_etai, cv_etae = cv * r_etae;
    float temp = cv_e * r_etae * ci_etai * chit;
    float den  = 1.0f - ff + ff * chit * (ile ? ci_etai : cv_etae);
    float shad = nz(temp * rcp(den), 0.0f);  // ff=inf -> den=NaN -> 0 (matches ref)

    // B0/(1 + tan(g/2)/h) + 1 = B0*h/(h + tg2) + 1; tan(g/2)=sqrt((1-cg)/(1+cg))
    float tg2 = sqf((1.0f - cg) * rcp(1.0f + cg));
    float hh  = h[idx];
    float B   = B0[idx] * hh * rcp(hh + tg2) + 1.0f;
    float tmp1 = ci_e * rcp((ci_e + cv_e) * ci);

    float logi = 0.5f * __logf(fabsf((1.0f + ci_e) * rcp(ci_e)));
    float loge = 0.5f * __logf(fabsf((1.0f + cv_e) * rcp(cv_e)));

    float o[3];
    const float W3[3] = {wv.x, wv.y, wv.z};
    const float B3[3] = {bv.x, bv.y, bv.z};
    const float C3[3] = {cc.x, cc.y, cc.z};
    #pragma unroll
    for (int k = 0; k < 3; ++k) {
        float wk = W3[k], bk = B3[k], ck = C3[k];
        float b2 = bk * bk, bx = bk * cg;
        float t1 = 1.0f - 2.0f*bx + b2;      // >= (1-0.8)^2 = 0.04 > 0
        float t2 = 1.0f + 2.0f*bx + b2;
        float q1 = t1 * sqf(t1) + 1e-6f;
        float q2 = t2 * sqf(t2) + 1e-6f;
        float P  = (1.0f - b2) * (ck*q2 + (1.0f - ck)*q1) * rcp(q1*q2);
        float gamma = sqf(1.0f - wk);
        float ro = (1.0f - gamma) * rcp(1.0f + gamma);
        float Hi = nz(rcp(1.0f - wk*ci_e*(ro + (1.0f - 2.0f*ro*ci_e)*logi)), 1.0f);
        float Hv = nz(rcp(1.0f - wk*cv_e*(ro + (1.0f - 2.0f*ro*cv_e)*loge)), 1.0f);
        float tmp2 = P * B + Hi * Hv - 1.0f;
        o[k] = wk * 0.25f * tmp1 * tmp2 * shad;   // w / HPK_SCL
    }
    f3 ov = {o[0], o[1], o[2]};
    out[idx] = ov;                            // one global_store_dwordx3
}

extern "C" void kernel_launch(void* const* d_in, const int* in_sizes, int n_in,
                              void* d_out, int out_size, void* d_ws, size_t ws_size,
                              hipStream_t stream) {
    const f3* pts2l  = (const f3*)d_in[0];
    const f3* pts2c  = (const f3*)d_in[1];
    const f3* normal = (const f3*)d_in[2];
    const f3* w      = (const f3*)d_in[3];
    const f3* b      = (const f3*)d_in[4];
    const f3* c      = (const f3*)d_in[5];
    const float* theta = (const float*)d_in[6];
    const float* h     = (const float*)d_in[7];
    const float* B0    = (const float*)d_in[8];
    f3* out = (f3*)d_out;

    int N = in_sizes[6];
    const int block = 256;
    int grid = (N + block - 1) / block;
    hapke_kernel<<<grid, block, 0, stream>>>(pts2l, pts2c, normal, w, b, c,
                                             theta, h, B0, out, N);
}